// Round 3
// baseline (395.075 us; speedup 1.0000x reference)
//
#include <hip/hip_runtime.h>

// NeuralSumProductModel: weighted sum-product LDPC decoder.
// N=8192 vars, M=4096 checks, DV=3, DC=6, ITERS=5, B=1024, E=24576.
// One block per batch row; thread t owns 24 contiguous edges = 8 variables.
//
// R6 change vs R5 (250 µs, FETCH 160MB / WRITE 271MB = ~20 regs scratch-
// spilled): the allocator pins this kernel at 64 arch VGPRs + 64 AGPRs
// (128 unified split, confirmed twice: launch_bounds(,4) in R4 and
// waves_per_eu(4,4) in R5 both left VGPR_Count=64 and spilled). So:
//  1. Persistent state em[24] + llr_v[8] is MANUALLY placed in AGPRs via
//     v_accvgpr_read/write inline asm -- using the 64 acc registers the
//     allocator reserves but never touches. ~500 extra VALU moves/thread
//     (~2 us) replaces ~90 MB/dispatch of scratch round-trip.
//  2. Phase A processed in two 4-variable chunks separated by
//     sched_barrier(0): caps in-flight weight loads at 24 values (the
//     full 8-var unroll hoisted 48 -> the spill trigger). Chunks are an
//     inlined lambda with literal v0 so all pa[]/em[] indices stay
//     compile-time constant (no runtime-indexed arrays -> no scratch).
//
// Carried from R4/R5:
//  * em in regs (was LDS): R3->R4 cut SQ_LDS_BANK_CONFLICT 5.0e7 -> 2.0e7.
//  * CSTRIDE=7 (gcd(7,32)=1): A2's lane-stride-7 reads conflict-free.
//  * div7 magic: floor(a/7) = (a*18725)>>17, exact for a<=28671.
// Arithmetic is op-for-op identical to R3/R4/R5 -> identical output.

#define N_VARS 8192
#define M_CHK  4096
#define ITERS  5
#define BATCH  1024
#define NEDGE  (N_VARS * 3)     // 24576
#define TPB    1024
#define EPT    (NEDGE / TPB)    // 24 edges / thread
#define VPT    (N_VARS / TPB)   // 8 variables / thread
#define CPT    (M_CHK / TPB)    // 4 checks / thread
#define CSTRIDE 7               // padded check stride: conflict-free A2 reads

#define LOG2E_F 1.44269504f
#define LN2_F   0.69314718f
#define M_CLIP  39.863137f      // -log2(1e-12)
#define E_CLIP  0.99999988f     // float32(1 - 1e-7)

// AGPR stash: value lives in an AGPR-class vreg between W and R.
#define AG_W(slot, val) asm("v_accvgpr_write_b32 %0, %1" : "=a"(slot) : "v"(val))
#define AG_R(slot, dst) asm("v_accvgpr_read_b32 %0, %1"  : "=v"(dst)  : "a"(slot))

// packed edge message: bits[30:0] = m = -log2|tanh(x/2)| (>=0), bit31 = (x<0)
__device__ __forceinline__ float edge_msg(float x) {
    float a  = fabsf(x);
    float ee = __builtin_amdgcn_exp2f(-a * LOG2E_F);          // e^{-|x|}
    float m  = __builtin_amdgcn_logf(1.0f + ee) - __builtin_amdgcn_logf(1.0f - ee);
    m = fminf(m, M_CLIP);
    unsigned neg = (x < 0.0f) ? 0x80000000u : 0u;
    return __uint_as_float(__float_as_uint(m) | neg);
}

// c = addr/7, exact for addr <= 28671: floor(addr*18725/2^17)
// (proof: a=7q+r -> a*18725 = q*2^17 + 3q + 18725r; 3*4095+18725*6 < 2^17)
__device__ __forceinline__ unsigned div7(unsigned a) {
    return (a * 18725u) >> 17;
}

// ---- setup: per-edge LDS slot addr = c*7 + rank-within-check
__global__ void setup_slots(const int* __restrict__ chk,
                            unsigned* __restrict__ tbl,
                            int* __restrict__ cnt) {
    int e = blockIdx.x * 256 + threadIdx.x;
    if (e < NEDGE) {
        int c = chk[e];
        int slot = atomicAdd(&cnt[c], 1);
        tbl[e] = (unsigned)(c * CSTRIDE + slot);  // < 28672, fits 16 bits
    }
}

__global__ void __launch_bounds__(TPB, 4)
nsp_kernel(const float* __restrict__ llr,
           const float* __restrict__ vw,
           const float* __restrict__ cw,
           const unsigned* __restrict__ tbl,
           float* __restrict__ out)
{
    __shared__ float    lds_m[M_CHK * CSTRIDE];  // 112 KB: msgs at c*7+slot
    __shared__ unsigned chk_tot[M_CHK];          // 16 KB: packed (S, parity)

    const int b  = blockIdx.x;
    const int t  = threadIdx.x;
    const int e0 = t * EPT;
    const int n0 = t * VPT;

    // AGPR-resident persistent state (allocator gives us 64 acc regs free):
    float em[EPT];     // per-edge msg (A) / check msg r (B); 24 AGPRs
    float llr_a[VPT];  // my 8 llr values; 8 AGPRs

    {
        const float4* p = (const float4*)(llr + (size_t)b * N_VARS + n0);
        float4 a = p[0], c = p[1];
        AG_W(llr_a[0], a.x); AG_W(llr_a[1], a.y);
        AG_W(llr_a[2], a.z); AG_W(llr_a[3], a.w);
        AG_W(llr_a[4], c.x); AG_W(llr_a[5], c.y);
        AG_W(llr_a[6], c.z); AG_W(llr_a[7], c.w);
    }

    // 16-bit LDS addrs for my 24 edges, packed 2/reg (12 arch VGPRs)
    unsigned pa[EPT / 2];
    {
        const uint4* p = (const uint4*)(tbl + e0);
#pragma unroll
        for (int k = 0; k < EPT / 4; ++k) {
            uint4 v = p[k];
            pa[2 * k]     = v.x | (v.y << 16);
            pa[2 * k + 1] = v.z | (v.w << 16);
        }
    }
#define ADDR(e) ((pa[(e) >> 1] >> (((e) & 1) * 16)) & 0xFFFFu)

    // Phase A body for 4 variables starting at v0 (v0 must be a literal so
    // every pa/em index is compile-time constant).
    auto phaseA4 = [&](int v0, const float* cwr, const float* vwr,
                       float* op) {
        float outb[4];
#pragma unroll
        for (int vv = 0; vv < 4; ++vv) {
            const int v = v0 + vv;
            float r0, r1, r2, lv;
            AG_R(em[3 * v + 0], r0);
            AG_R(em[3 * v + 1], r1);
            AG_R(em[3 * v + 2], r2);
            AG_R(llr_a[v], lv);
            float x0 = r0 * cwr[3 * v + 0];
            float x1 = r1 * cwr[3 * v + 1];
            float x2 = r2 * cwr[3 * v + 2];
            float s  = x0 + x1 + x2;
            outb[vv] = s + lv;              // output row it-1 (fused)
#pragma unroll
            for (int j = 0; j < 3; ++j) {
                const int e = 3 * v + j;
                float extj = (j == 0) ? x0 : (j == 1) ? x1 : x2;
                float x = (s - extj) * vwr[e] + lv;
                float p = edge_msg(x);
                AG_W(em[e], p);
                lds_m[ADDR(e)] = p;
            }
        }
        *((float4*)(op + v0)) = make_float4(outb[0], outb[1], outb[2], outb[3]);
    };

    for (int it = 0; it < ITERS; ++it) {
        // ---- Phase A: variable-node LOO + log-domain msg
        // writes em[] (for this thread's Phase B) and scatter-writes lds_m
        // (for Phase A2's cross-thread check gather).
        if (it == 0) {
#pragma unroll
            for (int v = 0; v < VPT; ++v) {
                float lv;
                AG_R(llr_a[v], lv);
                float p = edge_msg(lv);     // ext==0: same msg on 3 edges
#pragma unroll
                for (int j = 0; j < 3; ++j) {
                    AG_W(em[3 * v + j], p);
                    lds_m[ADDR(3 * v + j)] = p;
                }
            }
        } else {
            const float* cwr = cw + (size_t)(it - 1) * NEDGE + e0;
            const float* vwr = vw + (size_t)it * NEDGE + e0;
            float* op = out + ((size_t)(it - 1) * BATCH + b) * N_VARS + n0;
            phaseA4(0, cwr, vwr, op);
            __builtin_amdgcn_sched_barrier(0);   // don't merge chunk loads
            phaseA4(4, cwr, vwr, op);
        }
        __syncthreads();

        // ---- Phase A2: per-check reduction; c = t + k*1024.
        // lane stride = 7 words, gcd(7,32)=1 -> all 32 banks, 2 lanes/bank
        // = conflict-free.
#pragma unroll
        for (int k = 0; k < CPT; ++k) {
            int c = t + k * TPB;
            const float* q = lds_m + c * CSTRIDE;
            unsigned u0 = __float_as_uint(q[0]);
            unsigned u1 = __float_as_uint(q[1]);
            unsigned u2 = __float_as_uint(q[2]);
            unsigned u3 = __float_as_uint(q[3]);
            unsigned u4 = __float_as_uint(q[4]);
            unsigned u5 = __float_as_uint(q[5]);
            float S = __uint_as_float(u0 & 0x7fffffffu)
                    + __uint_as_float(u1 & 0x7fffffffu)
                    + __uint_as_float(u2 & 0x7fffffffu)
                    + __uint_as_float(u3 & 0x7fffffffu)
                    + __uint_as_float(u4 & 0x7fffffffu)
                    + __uint_as_float(u5 & 0x7fffffffu);
            unsigned P = (u0 ^ u1 ^ u2 ^ u3 ^ u4 ^ u5) & 0x80000000u;
            chk_tot[c] = __float_as_uint(S) | P;   // S>=0 so bit31 free
        }
        __syncthreads();

        // ---- Phase B: per-edge LOO + 2*atanh; msg from em[] (AGPR), only
        // chk_tot is gathered from LDS; result r goes back to em[] (AGPR).
#pragma unroll
        for (int e = 0; e < EPT; ++e) {
            unsigned ad = ADDR(e);
            float mv;
            AG_R(em[e], mv);
            unsigned u  = __float_as_uint(mv);
            float m  = __uint_as_float(u & 0x7fffffffu);
            unsigned T = chk_tot[div7(ad)];
            float S  = __uint_as_float(T & 0x7fffffffu);
            unsigned P = (T ^ u) & 0x80000000u;      // LOO parity
            float E = __builtin_amdgcn_exp2f(m - S); // prod of other |t|
            E = fminf(E, E_CLIP);
            float r = LN2_F * (__builtin_amdgcn_logf(1.0f + E)
                             - __builtin_amdgcn_logf(1.0f - E)); // 2*atanh
            AG_W(em[e], __uint_as_float(__float_as_uint(r) ^ P));
        }
        // no barrier: next Phase A reads only em[] (AGPRs); the next
        // cross-thread LDS reader (A2) is behind barrier 1, and B's chk_tot
        // reads complete before this thread reaches that barrier.
    }

    // ---- final output row: ext = r * cnode_w[ITERS-1], r in AGPRs
    {
        const float* cwr = cw + (size_t)(ITERS - 1) * NEDGE + e0;
        float outb[VPT];
#pragma unroll
        for (int v = 0; v < VPT; ++v) {
            float r0, r1, r2, lv;
            AG_R(em[3 * v + 0], r0);
            AG_R(em[3 * v + 1], r1);
            AG_R(em[3 * v + 2], r2);
            AG_R(llr_a[v], lv);
            outb[v] = r0 * cwr[3 * v]
                    + r1 * cwr[3 * v + 1]
                    + r2 * cwr[3 * v + 2]
                    + lv;
        }
        float* op = out + ((size_t)(ITERS - 1) * BATCH + b) * N_VARS + n0;
        ((float4*)op)[0] = make_float4(outb[0], outb[1], outb[2], outb[3]);
        ((float4*)op)[1] = make_float4(outb[4], outb[5], outb[6], outb[7]);
    }
#undef ADDR
}

extern "C" void kernel_launch(void* const* d_in, const int* in_sizes, int n_in,
                              void* d_out, int out_size, void* d_ws, size_t ws_size,
                              hipStream_t stream) {
    const float* llr = (const float*)d_in[0];   // (B, N)
    const float* vw  = (const float*)d_in[1];   // (ITERS, E)
    const float* cw  = (const float*)d_in[2];   // (ITERS, E)
    // d_in[3] = var_idx (unused: edges are variable-major, var = e/3)
    const int*   chk = (const int*)d_in[4];     // (E,)
    float* out = (float*)d_out;                 // (ITERS, B, N) f32

    // ws layout: [0, 96KB) u32 tbl[NEDGE]; [96KB, +16KB) int cnt[M_CHK]
    unsigned* tbl = (unsigned*)d_ws;
    int*      cnt = (int*)((char*)d_ws + NEDGE * sizeof(unsigned));

    hipMemsetAsync(cnt, 0, M_CHK * sizeof(int), stream);
    setup_slots<<<(NEDGE + 255) / 256, 256, 0, stream>>>(chk, tbl, cnt);
    nsp_kernel<<<BATCH, TPB, 0, stream>>>(llr, vw, cw, tbl, out);
}

// Round 4
// 339.122 us; speedup vs baseline: 1.1650x; 1.1650x over previous
//
#include <hip/hip_runtime.h>

// NeuralSumProductModel: weighted sum-product LDPC decoder.
// N=8192 vars, M=4096 checks, DV=3, DC=6, ITERS=5, B=1024, E=24576.
// One block per batch row; thread t owns 24 contiguous edges = 8 variables
// (variable side) and 4 checks (check side).
//
// R7 change vs R6 (256.5 µs, spills fixed but flat): MERGE Phase B into
// Phase A2. The check-owner thread holds all 6 messages of its check after
// conflict-free stride-7 reads; it computes the 6 leave-one-out r values
// in place and writes them back to the SAME slots (stride-7, conflict-free).
//   * Phase B (24 dependent random chk_tot reads/thread, the worst latency
//     structure in the kernel) is gone; next Phase A reads r directly from
//     lds_m[ADDR(e)] (random read count/thread unchanged: 48/iter).
//   * chk_tot (16 KB) gone -> LDS 112 KB. div7 gone. em[] AGPR array and
//     its ~500 moves/thread gone.
//   * Iteration is now 2 balanced phases between 2 barriers (was big/tiny/
//     medium across the same 2 barriers -> A2's utilization dip removed).
//   * Phase A batches its 12 random r-reads per 4-var chunk before any
//     LDS write (LDS alias rules would otherwise serialize read/write).
//
// Arithmetic is bit-identical to R4/R5/R6: same S add order, same parity
// identity ((P^u)&sign == (T^u)&sign), same E/clip/log chain, same output
// fusion. Expect absmax == 0.015625 exactly.
//
// R6 lesson kept: scratch spills at 11% HBM were harmless, so no AGPR
// heroics needed; persistent arch state is just pa[12]+llr_v[8] ~ 20 regs.

#define N_VARS 8192
#define M_CHK  4096
#define ITERS  5
#define BATCH  1024
#define NEDGE  (N_VARS * 3)     // 24576
#define TPB    1024
#define EPT    (NEDGE / TPB)    // 24 edges / thread
#define VPT    (N_VARS / TPB)   // 8 variables / thread
#define CPT    (M_CHK / TPB)    // 4 checks / thread
#define CSTRIDE 7               // padded check stride: conflict-free stride-7

#define LOG2E_F 1.44269504f
#define LN2_F   0.69314718f
#define M_CLIP  39.863137f      // -log2(1e-12)
#define E_CLIP  0.99999988f     // float32(1 - 1e-7)

// packed edge message: bits[30:0] = m = -log2|tanh(x/2)| (>=0), bit31 = (x<0)
__device__ __forceinline__ float edge_msg(float x) {
    float a  = fabsf(x);
    float ee = __builtin_amdgcn_exp2f(-a * LOG2E_F);          // e^{-|x|}
    float m  = __builtin_amdgcn_logf(1.0f + ee) - __builtin_amdgcn_logf(1.0f - ee);
    m = fminf(m, M_CLIP);
    unsigned neg = (x < 0.0f) ? 0x80000000u : 0u;
    return __uint_as_float(__float_as_uint(m) | neg);
}

// ---- setup: per-edge LDS slot addr = c*7 + rank-within-check
__global__ void setup_slots(const int* __restrict__ chk,
                            unsigned* __restrict__ tbl,
                            int* __restrict__ cnt) {
    int e = blockIdx.x * 256 + threadIdx.x;
    if (e < NEDGE) {
        int c = chk[e];
        int slot = atomicAdd(&cnt[c], 1);
        tbl[e] = (unsigned)(c * CSTRIDE + slot);  // < 28672, fits 16 bits
    }
}

__global__ void __launch_bounds__(TPB, 4)
nsp_kernel(const float* __restrict__ llr,
           const float* __restrict__ vw,
           const float* __restrict__ cw,
           const unsigned* __restrict__ tbl,
           float* __restrict__ out)
{
    __shared__ float lds_m[M_CHK * CSTRIDE];  // 112 KB: per-edge state at
                                              // c*7+slot. Phase A leaves the
                                              // packed msg here; A2B leaves
                                              // the signed check msg r here.

    const int b  = blockIdx.x;
    const int t  = threadIdx.x;
    const int e0 = t * EPT;
    const int n0 = t * VPT;

    // llr for my 8 variables (plain VGPRs; persistent arch ~20 regs total)
    float llr_v[VPT];
    {
        const float4* p = (const float4*)(llr + (size_t)b * N_VARS + n0);
        float4 a = p[0], c = p[1];
        llr_v[0] = a.x; llr_v[1] = a.y; llr_v[2] = a.z; llr_v[3] = a.w;
        llr_v[4] = c.x; llr_v[5] = c.y; llr_v[6] = c.z; llr_v[7] = c.w;
    }

    // 16-bit LDS addrs for my 24 edges, packed 2/reg (12 VGPRs)
    unsigned pa[EPT / 2];
    {
        const uint4* p = (const uint4*)(tbl + e0);
#pragma unroll
        for (int k = 0; k < EPT / 4; ++k) {
            uint4 v = p[k];
            pa[2 * k]     = v.x | (v.y << 16);
            pa[2 * k + 1] = v.z | (v.w << 16);
        }
    }
#define ADDR(e) ((pa[(e) >> 1] >> (((e) & 1) * 16)) & 0xFFFFu)

    // Phase A body for 4 variables starting at v0 (v0 literal so every
    // pa index is compile-time constant). Batches all 12 random r-reads
    // BEFORE the first LDS write: LDS aliasing otherwise forces the
    // compiler to serialize read/write per variable.
    auto phaseA4 = [&](int v0, const float* cwr, const float* vwr,
                       float* op) {
        float rr[12];
#pragma unroll
        for (int q = 0; q < 12; ++q)
            rr[q] = lds_m[ADDR(3 * v0 + q)];
        float outb[4];
#pragma unroll
        for (int vv = 0; vv < 4; ++vv) {
            const int v = v0 + vv;
            float x0 = rr[3 * vv + 0] * cwr[3 * v + 0];
            float x1 = rr[3 * vv + 1] * cwr[3 * v + 1];
            float x2 = rr[3 * vv + 2] * cwr[3 * v + 2];
            float s  = x0 + x1 + x2;
            outb[vv] = s + llr_v[v];            // output row it-1 (fused)
#pragma unroll
            for (int j = 0; j < 3; ++j) {
                const int e = 3 * v + j;
                float extj = (j == 0) ? x0 : (j == 1) ? x1 : x2;
                float x = (s - extj) * vwr[e] + llr_v[v];
                lds_m[ADDR(e)] = edge_msg(x);   // own slot: no hazard
            }
        }
        *((float4*)(op + v0)) = make_float4(outb[0], outb[1], outb[2], outb[3]);
    };

    for (int it = 0; it < ITERS; ++it) {
        // ---- Phase A: variable-node LOO + log-domain msg.
        // Reads prev r from own slots (written by A2B behind barrier 2),
        // overwrites the same slots with the new packed message.
        if (it == 0) {
#pragma unroll
            for (int v = 0; v < VPT; ++v) {
                float p = edge_msg(llr_v[v]);   // ext==0: same msg on 3 edges
#pragma unroll
                for (int j = 0; j < 3; ++j)
                    lds_m[ADDR(3 * v + j)] = p;
            }
        } else {
            const float* cwr = cw + (size_t)(it - 1) * NEDGE + e0;
            const float* vwr = vw + (size_t)it * NEDGE + e0;
            float* op = out + ((size_t)(it - 1) * BATCH + b) * N_VARS + n0;
            phaseA4(0, cwr, vwr, op);
            __builtin_amdgcn_sched_barrier(0);  // cap chunk weight hoisting
            phaseA4(4, cwr, vwr, op);
        }
        __syncthreads();   // barrier 1: all msgs visible to check owners

        // ---- Phase A2B: per-check reduction + per-edge LOO + 2*atanh,
        // written back in place. c = t + k*1024 -> lane stride 7 words,
        // gcd(7,32)=1: reads AND writes are conflict-free. All 6 reads
        // complete (same thread) before the first write to those slots.
#pragma unroll
        for (int k = 0; k < CPT; ++k) {
            const int base = (t + k * TPB) * CSTRIDE;
            unsigned u0 = __float_as_uint(lds_m[base + 0]);
            unsigned u1 = __float_as_uint(lds_m[base + 1]);
            unsigned u2 = __float_as_uint(lds_m[base + 2]);
            unsigned u3 = __float_as_uint(lds_m[base + 3]);
            unsigned u4 = __float_as_uint(lds_m[base + 4]);
            unsigned u5 = __float_as_uint(lds_m[base + 5]);
            // same add order as previous rounds -> bit-identical S
            float S = __uint_as_float(u0 & 0x7fffffffu)
                    + __uint_as_float(u1 & 0x7fffffffu)
                    + __uint_as_float(u2 & 0x7fffffffu)
                    + __uint_as_float(u3 & 0x7fffffffu)
                    + __uint_as_float(u4 & 0x7fffffffu)
                    + __uint_as_float(u5 & 0x7fffffffu);
            unsigned P = (u0 ^ u1 ^ u2 ^ u3 ^ u4 ^ u5) & 0x80000000u;
#pragma unroll
            for (int i = 0; i < 6; ++i) {
                unsigned ui = (i == 0) ? u0 : (i == 1) ? u1 : (i == 2) ? u2
                            : (i == 3) ? u3 : (i == 4) ? u4 : u5;
                float m  = __uint_as_float(ui & 0x7fffffffu);
                unsigned sg = (P ^ ui) & 0x80000000u;    // LOO parity
                float E = __builtin_amdgcn_exp2f(m - S); // prod of other |t|
                E = fminf(E, E_CLIP);
                float r = LN2_F * (__builtin_amdgcn_logf(1.0f + E)
                                 - __builtin_amdgcn_logf(1.0f - E)); // 2*atanh
                lds_m[base + i] = __uint_as_float(__float_as_uint(r) ^ sg);
            }
        }
        __syncthreads();   // barrier 2: all r visible to edge owners
    }

    // ---- final output row: ext = r * cnode_w[ITERS-1], r gathered from
    // own slots (random reads, batched 12 at a time).
    {
        const float* cwr = cw + (size_t)(ITERS - 1) * NEDGE + e0;
        float* op = out + ((size_t)(ITERS - 1) * BATCH + b) * N_VARS + n0;
        auto finalF4 = [&](int v0) {
            float rr[12];
#pragma unroll
            for (int q = 0; q < 12; ++q)
                rr[q] = lds_m[ADDR(3 * v0 + q)];
            float outb[4];
#pragma unroll
            for (int vv = 0; vv < 4; ++vv) {
                const int v = v0 + vv;
                outb[vv] = rr[3 * vv + 0] * cwr[3 * v + 0]
                         + rr[3 * vv + 1] * cwr[3 * v + 1]
                         + rr[3 * vv + 2] * cwr[3 * v + 2]
                         + llr_v[v];
            }
            *((float4*)(op + v0)) = make_float4(outb[0], outb[1],
                                                outb[2], outb[3]);
        };
        finalF4(0);
        finalF4(4);
    }
#undef ADDR
}

extern "C" void kernel_launch(void* const* d_in, const int* in_sizes, int n_in,
                              void* d_out, int out_size, void* d_ws, size_t ws_size,
                              hipStream_t stream) {
    const float* llr = (const float*)d_in[0];   // (B, N)
    const float* vw  = (const float*)d_in[1];   // (ITERS, E)
    const float* cw  = (const float*)d_in[2];   // (ITERS, E)
    // d_in[3] = var_idx (unused: edges are variable-major, var = e/3)
    const int*   chk = (const int*)d_in[4];     // (E,)
    float* out = (float*)d_out;                 // (ITERS, B, N) f32

    // ws layout: [0, 96KB) u32 tbl[NEDGE]; [96KB, +16KB) int cnt[M_CHK]
    unsigned* tbl = (unsigned*)d_ws;
    int*      cnt = (int*)((char*)d_ws + NEDGE * sizeof(unsigned));

    hipMemsetAsync(cnt, 0, M_CHK * sizeof(int), stream);
    setup_slots<<<(NEDGE + 255) / 256, 256, 0, stream>>>(chk, tbl, cnt);
    nsp_kernel<<<BATCH, TPB, 0, stream>>>(llr, vw, cw, tbl, out);
}

// Round 5
// 321.463 us; speedup vs baseline: 1.2290x; 1.0549x over previous
//
#include <hip/hip_runtime.h>

// NeuralSumProductModel: weighted sum-product LDPC decoder.
// N=8192 vars, M=4096 checks, DV=3, DC=6, ITERS=5, B=1024, E=24576.
// One block per batch row; thread t owns 24 contiguous edges = 8 variables
// (variable side) and 4 checks (check side).
//
// R8 change vs R7 (199.7 µs, VALUBusy 54%, ~half of it transcendentals):
// DROP THE LOG DOMAIN. The log/exp packing existed only to turn the
// leave-one-out product into a subtraction; after R7's merge the check
// owner holds all 6 tanh values in registers, so the 6 LOO products are
// 12 multiplies via prefix/suffix products, sign handled by signed
// multiplication (parity bit-tricks, M_CLIP, packing all deleted).
//   * Phase A stores t = tanh(x/2) = sign(x)*(1-ee)/(1+ee), ee=e^-|x|:
//     exp2 + rcp = 2 trans (was exp2 + 2 log2 = 3).
//   * A2B: loo_i = prefix_{i-1}*suffix_{i+1}; clamp to +-E_CLIP (med3);
//     r = LN2*(log2(1+p) - log2(1-p)) = 2 trans (was exp2 + 2 log2 = 3).
//   * 4 trans/edge/iter vs 6 (~720 -> 480 per thread), trans are
//     quarter-rate so this is ~25-30% of the VALU issue load.
// LDS access pattern is byte-identical to R7 (same slots, same counts) ->
// conflicts unchanged. Numerics: same function as reference (which also
// clips prod to +-(1-1e-7)); direct f32 product is MORE accurate than
// f32 exp(sum log). Reference's 1e-12 |t| floor only matters at
// |x|<2e-12, deviation ~2e-12 in r -> negligible.
//
// Carried: R7 merged A2B (check-owner computes r in place, Phase B gone);
// CSTRIDE=7 conflict-free structured phase; batched random reads in A.

#define N_VARS 8192
#define M_CHK  4096
#define ITERS  5
#define BATCH  1024
#define NEDGE  (N_VARS * 3)     // 24576
#define TPB    1024
#define EPT    (NEDGE / TPB)    // 24 edges / thread
#define VPT    (N_VARS / TPB)   // 8 variables / thread
#define CPT    (M_CHK / TPB)    // 4 checks / thread
#define CSTRIDE 7               // padded check stride: conflict-free stride-7

#define LOG2E_F 1.44269504f
#define LN2_F   0.69314718f
#define E_CLIP  0.99999988f     // float32(1 - 1e-7)

// t = tanh(x/2), sign carried in the float itself
__device__ __forceinline__ float tanh_half(float x) {
    float a  = fabsf(x);
    float ee = __builtin_amdgcn_exp2f(-a * LOG2E_F);     // e^{-|x|}
    float tt = (1.0f - ee) * __builtin_amdgcn_rcpf(1.0f + ee);
    unsigned sg = __float_as_uint(x) & 0x80000000u;
    return __uint_as_float(__float_as_uint(tt) | sg);
}

// r = 2*atanh(clamp(p)) ; p in [-1,1]
__device__ __forceinline__ float atanh2(float p) {
    p = fminf(fmaxf(p, -E_CLIP), E_CLIP);                // med3 clamp
    return LN2_F * (__builtin_amdgcn_logf(1.0f + p)
                  - __builtin_amdgcn_logf(1.0f - p));    // log2 pair
}

// ---- setup: per-edge LDS slot addr = c*7 + rank-within-check
__global__ void setup_slots(const int* __restrict__ chk,
                            unsigned* __restrict__ tbl,
                            int* __restrict__ cnt) {
    int e = blockIdx.x * 256 + threadIdx.x;
    if (e < NEDGE) {
        int c = chk[e];
        int slot = atomicAdd(&cnt[c], 1);
        tbl[e] = (unsigned)(c * CSTRIDE + slot);  // < 28672, fits 16 bits
    }
}

__global__ void __launch_bounds__(TPB, 4)
nsp_kernel(const float* __restrict__ llr,
           const float* __restrict__ vw,
           const float* __restrict__ cw,
           const unsigned* __restrict__ tbl,
           float* __restrict__ out)
{
    __shared__ float lds_m[M_CHK * CSTRIDE];  // 112 KB: per-edge state at
                                              // c*7+slot. Phase A leaves
                                              // t=tanh(x/2) here; A2B leaves
                                              // the signed check msg r here.

    const int b  = blockIdx.x;
    const int t  = threadIdx.x;
    const int e0 = t * EPT;
    const int n0 = t * VPT;

    // llr for my 8 variables
    float llr_v[VPT];
    {
        const float4* p = (const float4*)(llr + (size_t)b * N_VARS + n0);
        float4 a = p[0], c = p[1];
        llr_v[0] = a.x; llr_v[1] = a.y; llr_v[2] = a.z; llr_v[3] = a.w;
        llr_v[4] = c.x; llr_v[5] = c.y; llr_v[6] = c.z; llr_v[7] = c.w;
    }

    // 16-bit LDS addrs for my 24 edges, packed 2/reg (12 VGPRs)
    unsigned pa[EPT / 2];
    {
        const uint4* p = (const uint4*)(tbl + e0);
#pragma unroll
        for (int k = 0; k < EPT / 4; ++k) {
            uint4 v = p[k];
            pa[2 * k]     = v.x | (v.y << 16);
            pa[2 * k + 1] = v.z | (v.w << 16);
        }
    }
#define ADDR(e) ((pa[(e) >> 1] >> (((e) & 1) * 16)) & 0xFFFFu)

    // Phase A body for 4 variables starting at v0 (v0 literal so every
    // pa index is compile-time constant). Batches all 12 random r-reads
    // BEFORE the first LDS write (LDS aliasing would otherwise serialize).
    auto phaseA4 = [&](int v0, const float* cwr, const float* vwr,
                       float* op) {
        float rr[12];
#pragma unroll
        for (int q = 0; q < 12; ++q)
            rr[q] = lds_m[ADDR(3 * v0 + q)];
        float outb[4];
#pragma unroll
        for (int vv = 0; vv < 4; ++vv) {
            const int v = v0 + vv;
            float x0 = rr[3 * vv + 0] * cwr[3 * v + 0];
            float x1 = rr[3 * vv + 1] * cwr[3 * v + 1];
            float x2 = rr[3 * vv + 2] * cwr[3 * v + 2];
            float s  = x0 + x1 + x2;
            outb[vv] = s + llr_v[v];            // output row it-1 (fused)
#pragma unroll
            for (int j = 0; j < 3; ++j) {
                const int e = 3 * v + j;
                float extj = (j == 0) ? x0 : (j == 1) ? x1 : x2;
                float x = (s - extj) * vwr[e] + llr_v[v];
                lds_m[ADDR(e)] = tanh_half(x);  // own slot: no hazard
            }
        }
        *((float4*)(op + v0)) = make_float4(outb[0], outb[1], outb[2], outb[3]);
    };

    for (int it = 0; it < ITERS; ++it) {
        // ---- Phase A: variable-node LOO, store t = tanh(x/2) per edge.
        if (it == 0) {
#pragma unroll
            for (int v = 0; v < VPT; ++v) {
                float p = tanh_half(llr_v[v]);  // ext==0: same t on 3 edges
#pragma unroll
                for (int j = 0; j < 3; ++j)
                    lds_m[ADDR(3 * v + j)] = p;
            }
        } else {
            const float* cwr = cw + (size_t)(it - 1) * NEDGE + e0;
            const float* vwr = vw + (size_t)it * NEDGE + e0;
            float* op = out + ((size_t)(it - 1) * BATCH + b) * N_VARS + n0;
            phaseA4(0, cwr, vwr, op);
            __builtin_amdgcn_sched_barrier(0);  // cap chunk weight hoisting
            phaseA4(4, cwr, vwr, op);
        }
        __syncthreads();   // barrier 1: all t visible to check owners

        // ---- Phase A2B: leave-one-out product via prefix/suffix (12
        // mults, sign rides along) + 2*atanh, written back in place.
        // c = t + k*1024 -> lane stride 7 words, gcd(7,32)=1: reads AND
        // writes conflict-free. All 6 reads complete (same thread) before
        // the first write to those slots.
#pragma unroll
        for (int k = 0; k < CPT; ++k) {
            const int base = (t + k * TPB) * CSTRIDE;
            float t0 = lds_m[base + 0];
            float t1 = lds_m[base + 1];
            float t2 = lds_m[base + 2];
            float t3 = lds_m[base + 3];
            float t4 = lds_m[base + 4];
            float t5 = lds_m[base + 5];
            // prefix products
            float p1 = t0 * t1;
            float p2 = p1 * t2;
            float p3 = p2 * t3;
            float p4 = p3 * t4;
            // suffix products
            float s4 = t5 * t4;
            float s3 = s4 * t3;
            float s2 = s3 * t2;
            float s1 = s2 * t1;
            lds_m[base + 0] = atanh2(s1);        // t1*t2*t3*t4*t5
            lds_m[base + 1] = atanh2(t0 * s2);
            lds_m[base + 2] = atanh2(p1 * s3);
            lds_m[base + 3] = atanh2(p2 * s4);
            lds_m[base + 4] = atanh2(p3 * t5);
            lds_m[base + 5] = atanh2(p4);        // t0*t1*t2*t3*t4
        }
        __syncthreads();   // barrier 2: all r visible to edge owners
    }

    // ---- final output row: ext = r * cnode_w[ITERS-1], r gathered from
    // own slots (random reads, batched 12 at a time).
    {
        const float* cwr = cw + (size_t)(ITERS - 1) * NEDGE + e0;
        float* op = out + ((size_t)(ITERS - 1) * BATCH + b) * N_VARS + n0;
        auto finalF4 = [&](int v0) {
            float rr[12];
#pragma unroll
            for (int q = 0; q < 12; ++q)
                rr[q] = lds_m[ADDR(3 * v0 + q)];
            float outb[4];
#pragma unroll
            for (int vv = 0; vv < 4; ++vv) {
                const int v = v0 + vv;
                outb[vv] = rr[3 * vv + 0] * cwr[3 * v + 0]
                         + rr[3 * vv + 1] * cwr[3 * v + 1]
                         + rr[3 * vv + 2] * cwr[3 * v + 2]
                         + llr_v[v];
            }
            *((float4*)(op + v0)) = make_float4(outb[0], outb[1],
                                                outb[2], outb[3]);
        };
        finalF4(0);
        finalF4(4);
    }
#undef ADDR
}

extern "C" void kernel_launch(void* const* d_in, const int* in_sizes, int n_in,
                              void* d_out, int out_size, void* d_ws, size_t ws_size,
                              hipStream_t stream) {
    const float* llr = (const float*)d_in[0];   // (B, N)
    const float* vw  = (const float*)d_in[1];   // (ITERS, E)
    const float* cw  = (const float*)d_in[2];   // (ITERS, E)
    // d_in[3] = var_idx (unused: edges are variable-major, var = e/3)
    const int*   chk = (const int*)d_in[4];     // (E,)
    float* out = (float*)d_out;                 // (ITERS, B, N) f32

    // ws layout: [0, 96KB) u32 tbl[NEDGE]; [96KB, +16KB) int cnt[M_CHK]
    unsigned* tbl = (unsigned*)d_ws;
    int*      cnt = (int*)((char*)d_ws + NEDGE * sizeof(unsigned));

    hipMemsetAsync(cnt, 0, M_CHK * sizeof(int), stream);
    setup_slots<<<(NEDGE + 255) / 256, 256, 0, stream>>>(chk, tbl, cnt);
    nsp_kernel<<<BATCH, TPB, 0, stream>>>(llr, vw, cw, tbl, out);
}

// Round 7
// 305.899 us; speedup vs baseline: 1.2915x; 1.0509x over previous
//
#include <hip/hip_runtime.h>

// NeuralSumProductModel: weighted sum-product LDPC decoder.
// N=8192 vars, M=4096 checks, DV=3, DC=6, ITERS=5, B=1024, E=24576.
// One block per batch row; thread t owns 24 contiguous edges = 8 variables
// (variable side) and 4 checks (check side).
//
// R10 = R9 resubmitted verbatim: the R9 bench died on container acquisition
// ("MI355X container failed twice"), not on the kernel. No counters were
// produced, so the R9 theory is still unmeasured.
//
// R9 change vs R8 (175 µs, VALU 41% / conflicts 18% / ~40% latency+barrier):
// SCHEDULING. Random-op count is at its structural floor (2E random + 2E
// structured LDS ops/iter: each edge crosses sides twice, one random op per
// crossing), occupancy is LDS-capped at 1 block/CU. What's left is phase-
// internal latency:
//  1. Phase A: ALL 24 random r-reads batched up front (one lgkmcnt region;
//     was 2x12 with a sched_barrier wall from the R6 register crisis that
//     no longer exists at VGPR=56). Two 4-var compute chunks keep peak
//     pressure ~55 < 64 cap.
//  2. Phase A2B: ALL 24 structured reads batched (one wait, was 4), then
//     4 independent check chains back-to-back -> trans-pipe ILP across
//     checks (48 quarter-rate trans per thread-iter was the critical chain).
//  3. Final gather batched the same way.
// Arithmetic is op-for-op identical to R8 -> absmax must stay 0.015625.
// Watch FETCH: jump above ~40 MB = batching re-triggered spills -> re-chunk.
//
// Carried: R7 merged A2B (check-owner computes r in place); R8 tanh domain
// (no log/exp packing, prefix/suffix LOO products, 4 trans/edge/iter);
// CSTRIDE=7 (gcd(7,32)=1) conflict-free structured phase.

#define N_VARS 8192
#define M_CHK  4096
#define ITERS  5
#define BATCH  1024
#define NEDGE  (N_VARS * 3)     // 24576
#define TPB    1024
#define EPT    (NEDGE / TPB)    // 24 edges / thread
#define VPT    (N_VARS / TPB)   // 8 variables / thread
#define CPT    (M_CHK / TPB)    // 4 checks / thread
#define CSTRIDE 7               // padded check stride: conflict-free stride-7

#define LOG2E_F 1.44269504f
#define LN2_F   0.69314718f
#define E_CLIP  0.99999988f     // float32(1 - 1e-7)

// t = tanh(x/2), sign carried in the float itself
__device__ __forceinline__ float tanh_half(float x) {
    float a  = fabsf(x);
    float ee = __builtin_amdgcn_exp2f(-a * LOG2E_F);     // e^{-|x|}
    float tt = (1.0f - ee) * __builtin_amdgcn_rcpf(1.0f + ee);
    unsigned sg = __float_as_uint(x) & 0x80000000u;
    return __uint_as_float(__float_as_uint(tt) | sg);
}

// r = 2*atanh(clamp(p)) ; p in [-1,1]
__device__ __forceinline__ float atanh2(float p) {
    p = fminf(fmaxf(p, -E_CLIP), E_CLIP);                // med3 clamp
    return LN2_F * (__builtin_amdgcn_logf(1.0f + p)
                  - __builtin_amdgcn_logf(1.0f - p));    // log2 pair
}

// ---- setup: per-edge LDS slot addr = c*7 + rank-within-check
__global__ void setup_slots(const int* __restrict__ chk,
                            unsigned* __restrict__ tbl,
                            int* __restrict__ cnt) {
    int e = blockIdx.x * 256 + threadIdx.x;
    if (e < NEDGE) {
        int c = chk[e];
        int slot = atomicAdd(&cnt[c], 1);
        tbl[e] = (unsigned)(c * CSTRIDE + slot);  // < 28672, fits 16 bits
    }
}

__global__ void __launch_bounds__(TPB, 4)
nsp_kernel(const float* __restrict__ llr,
           const float* __restrict__ vw,
           const float* __restrict__ cw,
           const unsigned* __restrict__ tbl,
           float* __restrict__ out)
{
    __shared__ float lds_m[M_CHK * CSTRIDE];  // 112 KB: per-edge state at
                                              // c*7+slot. Phase A leaves
                                              // t=tanh(x/2) here; A2B leaves
                                              // the signed check msg r here.

    const int b  = blockIdx.x;
    const int t  = threadIdx.x;
    const int e0 = t * EPT;
    const int n0 = t * VPT;

    // llr for my 8 variables
    float llr_v[VPT];
    {
        const float4* p = (const float4*)(llr + (size_t)b * N_VARS + n0);
        float4 a = p[0], c = p[1];
        llr_v[0] = a.x; llr_v[1] = a.y; llr_v[2] = a.z; llr_v[3] = a.w;
        llr_v[4] = c.x; llr_v[5] = c.y; llr_v[6] = c.z; llr_v[7] = c.w;
    }

    // 16-bit LDS addrs for my 24 edges, packed 2/reg (12 VGPRs)
    unsigned pa[EPT / 2];
    {
        const uint4* p = (const uint4*)(tbl + e0);
#pragma unroll
        for (int k = 0; k < EPT / 4; ++k) {
            uint4 v = p[k];
            pa[2 * k]     = v.x | (v.y << 16);
            pa[2 * k + 1] = v.z | (v.w << 16);
        }
    }
#define ADDR(e) ((pa[(e) >> 1] >> (((e) & 1) * 16)) & 0xFFFFu)

    // 4-var compute chunk (v0 literal -> all indices compile-time const).
    // rr = the 24 batched random r-reads (done by caller, one wait).
    auto computeA4 = [&](int v0, const float* cwr, const float* vwr,
                         float* op, const float* rr) {
        float outb[4];
#pragma unroll
        for (int vv = 0; vv < 4; ++vv) {
            const int v = v0 + vv;
            float x0 = rr[3 * v + 0] * cwr[3 * v + 0];
            float x1 = rr[3 * v + 1] * cwr[3 * v + 1];
            float x2 = rr[3 * v + 2] * cwr[3 * v + 2];
            float s  = x0 + x1 + x2;
            outb[vv] = s + llr_v[v];            // output row it-1 (fused)
#pragma unroll
            for (int j = 0; j < 3; ++j) {
                const int e = 3 * v + j;
                float extj = (j == 0) ? x0 : (j == 1) ? x1 : x2;
                float x = (s - extj) * vwr[e] + llr_v[v];
                lds_m[ADDR(e)] = tanh_half(x);  // own slot: no hazard
            }
        }
        *((float4*)(op + v0)) = make_float4(outb[0], outb[1], outb[2], outb[3]);
    };

    for (int it = 0; it < ITERS; ++it) {
        // ---- Phase A: variable-node LOO, store t = tanh(x/2) per edge.
        if (it == 0) {
#pragma unroll
            for (int v = 0; v < VPT; ++v) {
                float p = tanh_half(llr_v[v]);  // ext==0: same t on 3 edges
#pragma unroll
                for (int j = 0; j < 3; ++j)
                    lds_m[ADDR(3 * v + j)] = p;
            }
        } else {
            const float* cwr = cw + (size_t)(it - 1) * NEDGE + e0;
            const float* vwr = vw + (size_t)it * NEDGE + e0;
            float* op = out + ((size_t)(it - 1) * BATCH + b) * N_VARS + n0;
            // batch ALL 24 random reads: one lgkmcnt region
            float rr[EPT];
#pragma unroll
            for (int e = 0; e < EPT; ++e)
                rr[e] = lds_m[ADDR(e)];
            computeA4(0, cwr, vwr, op, rr);
            computeA4(4, cwr, vwr, op, rr);
        }
        __syncthreads();   // barrier 1: all t visible to check owners

        // ---- Phase A2B: leave-one-out product via prefix/suffix (12
        // mults, sign rides along) + 2*atanh, written back in place.
        // c = t + k*1024 -> lane stride 7 words, gcd(7,32)=1: reads AND
        // writes conflict-free. ALL 24 reads batched (one wait), then 4
        // independent check chains back-to-back for trans-pipe ILP.
        {
            float tv[CPT][6];
#pragma unroll
            for (int k = 0; k < CPT; ++k) {
                const int base = (t + k * TPB) * CSTRIDE;
#pragma unroll
                for (int i = 0; i < 6; ++i)
                    tv[k][i] = lds_m[base + i];
            }
#pragma unroll
            for (int k = 0; k < CPT; ++k) {
                const int base = (t + k * TPB) * CSTRIDE;
                float t0 = tv[k][0], t1 = tv[k][1], t2 = tv[k][2];
                float t3 = tv[k][3], t4 = tv[k][4], t5 = tv[k][5];
                // prefix products
                float p1 = t0 * t1;
                float p2 = p1 * t2;
                float p3 = p2 * t3;
                float p4 = p3 * t4;
                // suffix products
                float s4 = t5 * t4;
                float s3 = s4 * t3;
                float s2 = s3 * t2;
                float s1 = s2 * t1;
                lds_m[base + 0] = atanh2(s1);        // t1*t2*t3*t4*t5
                lds_m[base + 1] = atanh2(t0 * s2);
                lds_m[base + 2] = atanh2(p1 * s3);
                lds_m[base + 3] = atanh2(p2 * s4);
                lds_m[base + 4] = atanh2(p3 * t5);
                lds_m[base + 5] = atanh2(p4);        // t0*t1*t2*t3*t4
            }
        }
        __syncthreads();   // barrier 2: all r visible to edge owners
    }

    // ---- final output row: ext = r * cnode_w[ITERS-1]; 24 random reads
    // batched, then compute.
    {
        const float* cwr = cw + (size_t)(ITERS - 1) * NEDGE + e0;
        float* op = out + ((size_t)(ITERS - 1) * BATCH + b) * N_VARS + n0;
        float rr[EPT];
#pragma unroll
        for (int e = 0; e < EPT; ++e)
            rr[e] = lds_m[ADDR(e)];
        float outb[VPT];
#pragma unroll
        for (int v = 0; v < VPT; ++v) {
            outb[v] = rr[3 * v + 0] * cwr[3 * v + 0]
                    + rr[3 * v + 1] * cwr[3 * v + 1]
                    + rr[3 * v + 2] * cwr[3 * v + 2]
                    + llr_v[v];
        }
        ((float4*)op)[0] = make_float4(outb[0], outb[1], outb[2], outb[3]);
        ((float4*)op)[1] = make_float4(outb[4], outb[5], outb[6], outb[7]);
    }
#undef ADDR
}

extern "C" void kernel_launch(void* const* d_in, const int* in_sizes, int n_in,
                              void* d_out, int out_size, void* d_ws, size_t ws_size,
                              hipStream_t stream) {
    const float* llr = (const float*)d_in[0];   // (B, N)
    const float* vw  = (const float*)d_in[1];   // (ITERS, E)
    const float* cw  = (const float*)d_in[2];   // (ITERS, E)
    // d_in[3] = var_idx (unused: edges are variable-major, var = e/3)
    const int*   chk = (const int*)d_in[4];     // (E,)
    float* out = (float*)d_out;                 // (ITERS, B, N) f32

    // ws layout: [0, 96KB) u32 tbl[NEDGE]; [96KB, +16KB) int cnt[M_CHK]
    unsigned* tbl = (unsigned*)d_ws;
    int*      cnt = (int*)((char*)d_ws + NEDGE * sizeof(unsigned));

    hipMemsetAsync(cnt, 0, M_CHK * sizeof(int), stream);
    setup_slots<<<(NEDGE + 255) / 256, 256, 0, stream>>>(chk, tbl, cnt);
    nsp_kernel<<<BATCH, TPB, 0, stream>>>(llr, vw, cw, tbl, out);
}